// Round 11
// baseline (249.557 us; speedup 1.0000x reference)
//
#include <hip/hip_runtime.h>
#include <hip/hip_bf16.h>

#define N_NODES 50000
#define N_EDGES 800000
#define IN_CH 256
#define OUT_CH 64
#define NBLK_E 3125   // N_EDGES / 256
#define NBLK_N 196    // ceil(50000/256)

typedef __bf16 bfvec8 __attribute__((ext_vector_type(8)));
typedef float floatx4 __attribute__((ext_vector_type(4)));

// ---- ws layout (bytes), total ~18.7 MB ----
#define WS_WHB   0          // bf16 [50000][64]   6,400,000
#define WS_W32   6400000    // fp32 [800000]      3,200,000  CSR-placed weights
#define WS_PSRC  9600000    // u16  [800000]      1,600,000  CSR-placed src
#define WS_SRC16 11200000   // u16  [800000]      1,600,000
#define WS_DST16 12800000   // u16  [800000]      1,600,000
#define WS_WE    14400000   // fp32 [800000]      3,200,000  edge w (-1 = masked)
#define WS_CNT   17600000   // int  [50000]         200,000
#define WS_KEYS  17800000   // uint[2] {keyS,keyD}  (memset with CNT: 200,008 B)
#define WS_ROWP  17800016   // int  [50000]
#define WS_WOFS  18000016   // int  [50000]
#define WS_WTH   18200016   // bf16 [64][256]        32,768  (16B aligned)
#define WS_WTL   18232784   // bf16 [64][256]        32,768
#define WS_ESRC  18265552   // fp32 [50000]
#define WS_EDST  18465552   // fp32 [50000]
#define WS_BSUM  18665552   // fp32 [3125]
#define WS_BTOT  18678064   // int  [196]
#define WS_BBASE 18678848   // int  [196]
#define WS_Z     18679632
#define WS_FLAGS 18679636   // int[2]: {edge_is_i64, float_is_f32}

// ---------- helpers ----------
__device__ __forceinline__ unsigned encode_f(float f) {
    unsigned u = __float_as_uint(f);
    return (u & 0x80000000u) ? ~u : (u | 0x80000000u);
}
__device__ __forceinline__ float decode_f(unsigned u) {
    unsigned b = (u & 0x80000000u) ? (u & 0x7fffffffu) : ~u;
    return __uint_as_float(b);
}
__device__ __forceinline__ float loadf(const void* p, size_t i, int isf32) {
    return isf32 ? ((const float*)p)[i]
                 : __bfloat162float(((const __hip_bfloat16*)p)[i]);
}
__device__ __forceinline__ void load_edge(const int* __restrict__ ei, int i, int f64,
                                          int& s, int& d) {
    if (f64) {
        int2 ps = ((const int2*)ei)[i];
        int2 pd = ((const int2*)ei)[N_EDGES + i];
        s = ps.x; d = pd.x;
    } else {
        s = ei[i]; d = ei[N_EDGES + i];
    }
    s = min(max(s, 0), N_NODES - 1);
    d = min(max(d, 0), N_NODES - 1);
}

// ---------- K1: Wt hi/lo split-transpose; also computes dtype flags locally ----------
__global__ __launch_bounds__(256) void k_prep(const void* __restrict__ Wv,
                                              const int* __restrict__ ei,
                                              const unsigned* __restrict__ xw,
                                              int* __restrict__ flags,
                                              __bf16* __restrict__ Wth,
                                              __bf16* __restrict__ Wtl) {
    // per-block redundant dtype detection (no separate kernel / no dependency)
    int t = threadIdx.x;
    int v = 0;
    for (int i = t; i < 2048; i += 256) v |= ei[2 * i + 1];   // i64 high words == 0
    unsigned lo = xw[t] & 0xFFFFu;
    unsigned e8 = (lo >> 7) & 0xFFu;
    int hit = (e8 >= 96u && e8 <= 144u) ? 1 : 0;              // bf16-packed: ~all hit
#pragma unroll
    for (int off = 32; off > 0; off >>= 1) {
        v |= __shfl_down(v, off);
        hit += __shfl_down(hit, off);
    }
    __shared__ int sv[4], sh[4];
    if ((t & 63) == 0) { sv[t >> 6] = v; sh[t >> 6] = hit; }
    __syncthreads();
    __shared__ int s_isf;
    if (t == 0) {
        int f64 = ((sv[0] | sv[1] | sv[2] | sv[3]) == 0) ? 1 : 0;
        int isf = ((sh[0] + sh[1] + sh[2] + sh[3]) < 192) ? 1 : 0;
        flags[0] = f64;
        flags[1] = isf;
        s_isf = isf;
    }
    __syncthreads();
    int isf = s_isf;

    int g = blockIdx.x * 256 + t;   // 0..16383
    int c = g >> 8, k = g & 255;
    float w = loadf(Wv, (size_t)k * OUT_CH + c, isf);
    __bf16 h = (__bf16)w;
    Wth[g] = h;
    Wtl[g] = (__bf16)(w - (float)h);
}

// ---------- K2: wh = x @ W via split-bf16 MFMA; Wt in LDS; fused logits + node max ----------
__global__ __launch_bounds__(256, 2) void k_mm(const void* __restrict__ xv,
                                               const __bf16* __restrict__ Wth,
                                               const __bf16* __restrict__ Wtl,
                                               const void* __restrict__ av,
                                               const int* __restrict__ flags,
                                               __bf16* __restrict__ whb,
                                               float* __restrict__ esrc,
                                               float* __restrict__ edst,
                                               unsigned* __restrict__ keys) {
    __shared__ __bf16 lW[2][64 * 256];        // 64 KB
    int tid = threadIdx.x;
    int isf = flags[1];
    int gw = (blockIdx.x * 256 + tid) >> 6;
    int lane = tid & 63;
    int m = lane & 15, quad = lane >> 4;
    int nb = gw * 16;
    bool active = gw < N_NODES / 16;          // wave-uniform

    // hoisted x loads
    floatx4 x0[8], x1[8];
    bfvec8 xa[8];
    if (active) {
        if (isf) {
            const float* xr = (const float*)xv + (size_t)(nb + m) * IN_CH + quad * 8;
#pragma unroll
            for (int s = 0; s < 8; ++s) {
                x0[s] = *(const floatx4*)(xr + s * 32);
                x1[s] = *(const floatx4*)(xr + s * 32 + 4);
            }
        } else {
            const __bf16* xr = (const __bf16*)xv + (size_t)(nb + m) * IN_CH + quad * 8;
#pragma unroll
            for (int s = 0; s < 8; ++s) xa[s] = *(const bfvec8*)(xr + s * 32);
        }
    }

    // stage Wth/Wtl -> LDS, 16B chunks xor-swizzled (conflict-free ds_read_b128)
#pragma unroll
    for (int i = 0; i < 8; ++i) {
        int f = i * 256 + tid;
        int r = f >> 5, c = f & 31;
        int cs = c ^ (r & 31);
        *(bfvec8*)(&lW[0][r * 256 + cs * 8]) = *(const bfvec8*)(Wth + r * 256 + c * 8);
        *(bfvec8*)(&lW[1][r * 256 + cs * 8]) = *(const bfvec8*)(Wtl + r * 256 + c * 8);
    }
    __syncthreads();

    if (!active) return;

    floatx4 acc[4];
#pragma unroll
    for (int ct = 0; ct < 4; ++ct) acc[ct] = (floatx4){0.f, 0.f, 0.f, 0.f};

    if (isf) {
#pragma unroll
        for (int s = 0; s < 8; ++s) {
            float v[8];
            *(floatx4*)(v)     = x0[s];
            *(floatx4*)(v + 4) = x1[s];
            bfvec8 ahi, alo;
#pragma unroll
            for (int j = 0; j < 8; ++j) {
                __bf16 h = (__bf16)v[j];
                ahi[j] = h;
                alo[j] = (__bf16)(v[j] - (float)h);
            }
#pragma unroll
            for (int ct = 0; ct < 4; ++ct) {
                int row = ct * 16 + m;
                int cs = ((s * 4 + quad) ^ (row & 31)) * 8;
                bfvec8 bhi = *(const bfvec8*)(&lW[0][row * 256 + cs]);
                bfvec8 blo = *(const bfvec8*)(&lW[1][row * 256 + cs]);
                acc[ct] = __builtin_amdgcn_mfma_f32_16x16x32_bf16(ahi, blo, acc[ct], 0, 0, 0);
                acc[ct] = __builtin_amdgcn_mfma_f32_16x16x32_bf16(alo, bhi, acc[ct], 0, 0, 0);
                acc[ct] = __builtin_amdgcn_mfma_f32_16x16x32_bf16(ahi, bhi, acc[ct], 0, 0, 0);
            }
        }
    } else {
#pragma unroll
        for (int s = 0; s < 8; ++s) {
#pragma unroll
            for (int ct = 0; ct < 4; ++ct) {
                int row = ct * 16 + m;
                int cs = ((s * 4 + quad) ^ (row & 31)) * 8;
                bfvec8 bhi = *(const bfvec8*)(&lW[0][row * 256 + cs]);
                bfvec8 blo = *(const bfvec8*)(&lW[1][row * 256 + cs]);
                acc[ct] = __builtin_amdgcn_mfma_f32_16x16x32_bf16(xa[s], blo, acc[ct], 0, 0, 0);
                acc[ct] = __builtin_amdgcn_mfma_f32_16x16x32_bf16(xa[s], bhi, acc[ct], 0, 0, 0);
            }
        }
    }

    float a1[4], a2[4];
#pragma unroll
    for (int ct = 0; ct < 4; ++ct) {
        a1[ct] = loadf(av, ct * 16 + m, isf);
        a2[ct] = loadf(av, OUT_CH + ct * 16 + m, isf);
    }
    float mS = -3.0e38f, mD = -3.0e38f;
#pragma unroll
    for (int r = 0; r < 4; ++r) {
        int node = nb + quad * 4 + r;
        float s1 = 0.f, s2 = 0.f;
#pragma unroll
        for (int ct = 0; ct < 4; ++ct) {
            float vv = acc[ct][r];
            whb[(size_t)node * OUT_CH + ct * 16 + m] = (__bf16)vv;
            s1 += vv * a1[ct];
            s2 += vv * a2[ct];
        }
#pragma unroll
        for (int off = 1; off < 16; off <<= 1) {   // all 16 lanes of quad hold sum
            s1 += __shfl_xor(s1, off);
            s2 += __shfl_xor(s2, off);
        }
        if (m == 0) { esrc[node] = s1; edst[node] = s2; }
        mS = fmaxf(mS, s1);
        mD = fmaxf(mD, s2);
    }
    // wave max over its 16 nodes (reduce across quads)
#pragma unroll
    for (int mask = 16; mask <= 32; mask <<= 1) {
        mS = fmaxf(mS, __shfl_xor(mS, mask));
        mD = fmaxf(mD, __shfl_xor(mD, mask));
    }
    if (lane == 0) {
        atomicMax(&keys[0], encode_f(mS));   // keys memset to 0 == encode(-NaN), identity
        atomicMax(&keys[1], encode_f(mD));
    }
}

// ---------- K3: fused edge pass: score, exp(v-M'), histogram, block-sum, we[] ----------
__global__ __launch_bounds__(256) void k_edge(const int* __restrict__ ei,
                                              const int* __restrict__ flags,
                                              const unsigned* __restrict__ keys,
                                              const float* __restrict__ esrc,
                                              const float* __restrict__ edst,
                                              unsigned short* __restrict__ src16,
                                              unsigned short* __restrict__ dst16,
                                              float* __restrict__ we,
                                              int* __restrict__ cnt,
                                              float* __restrict__ bsum) {
    int f64 = flags[0];
    float Mp = decode_f(keys[0]) + decode_f(keys[1]);   // shift bound >= true max
    int i = blockIdx.x * 256 + threadIdx.x;
    int s, d;
    load_edge(ei, i, f64, s, d);
    src16[i] = (unsigned short)s;
    dst16[i] = (unsigned short)d;
    float v = esrc[s] + edst[d];
    float w, t;
    if (v > 0.0f) {
        w = expf(v - Mp);            // <= 1, no overflow; underflow -> 0 (placed, harmless)
        t = w;
        atomicAdd(&cnt[d], 1);
    } else {
        w = -1.0f;                   // sentinel: masked edge (true weight exactly 0)
        t = 0.0f;
    }
    we[i] = w;
#pragma unroll
    for (int off = 32; off > 0; off >>= 1) t += __shfl_down(t, off);
    __shared__ float sm[4];
    if ((threadIdx.x & 63) == 0) sm[threadIdx.x >> 6] = t;
    __syncthreads();
    if (threadIdx.x == 0) bsum[blockIdx.x] = sm[0] + sm[1] + sm[2] + sm[3];
}

// ---------- K4a: per-block scan of cnt ----------
__global__ __launch_bounds__(256) void k_scanA(const int* __restrict__ cnt,
                                               int* __restrict__ rowptr,
                                               int* __restrict__ btot) {
    int t = threadIdx.x, lane = t & 63, wid = t >> 6;
    int idx = blockIdx.x * 256 + t;
    int v = (idx < N_NODES) ? cnt[idx] : 0;
    int incl = v;
#pragma unroll
    for (int off = 1; off < 64; off <<= 1) {
        int u = __shfl_up(incl, off);
        if (lane >= off) incl += u;
    }
    __shared__ int wsum[4];
    if (lane == 63) wsum[wid] = incl;
    __syncthreads();
    int wbase = 0;
#pragma unroll
    for (int w = 0; w < 4; ++w) if (w < wid) wbase += wsum[w];
    if (idx < N_NODES) rowptr[idx] = wbase + incl - v;
    if (t == 255) btot[blockIdx.x] = wbase + incl;
}

// ---------- K4b: scan block totals + reduce bsum -> Z ----------
__global__ __launch_bounds__(256) void k_scanB(const int* __restrict__ btot,
                                               int* __restrict__ bbase,
                                               const float* __restrict__ bsum,
                                               float* __restrict__ Z) {
    int t = threadIdx.x, lane = t & 63, wid = t >> 6;
    float zs = 0.0f;
    for (int i = t; i < NBLK_E; i += 256) zs += bsum[i];
#pragma unroll
    for (int off = 32; off > 0; off >>= 1) zs += __shfl_down(zs, off);
    __shared__ float sz[4];
    if (lane == 0) sz[wid] = zs;

    int v = (t < NBLK_N) ? btot[t] : 0;
    int incl = v;
#pragma unroll
    for (int off = 1; off < 64; off <<= 1) {
        int u = __shfl_up(incl, off);
        if (lane >= off) incl += u;
    }
    __shared__ int wsum[4];
    if (lane == 63) wsum[wid] = incl;
    __syncthreads();
    int wbase = 0;
#pragma unroll
    for (int w = 0; w < 4; ++w) if (w < wid) wbase += wsum[w];
    if (t < NBLK_N) bbase[t] = wbase + incl - v;
    if (t == 0) *Z = sz[0] + sz[1] + sz[2] + sz[3];
}

// ---------- K4c: add block bases ----------
__global__ __launch_bounds__(256) void k_scanC(int* __restrict__ rowptr,
                                               int* __restrict__ wofs,
                                               const int* __restrict__ bbase) {
    int idx = blockIdx.x * 256 + threadIdx.x;
    if (idx < N_NODES) {
        int r = rowptr[idx] + bbase[blockIdx.x];
        rowptr[idx] = r;
        wofs[idx] = r;
    }
}

// ---------- K5: CSR placement (sequential reads, scattered 6B writes) ----------
__global__ __launch_bounds__(256) void k_place(const float* __restrict__ we,
                                               const unsigned short* __restrict__ src16,
                                               const unsigned short* __restrict__ dst16,
                                               int* __restrict__ wofs,
                                               float* __restrict__ w32,
                                               unsigned short* __restrict__ psrc) {
    int i = blockIdx.x * 256 + threadIdx.x;
    float w = we[i];
    if (w >= 0.0f) {
        int d = dst16[i];
        int pos = atomicAdd(&wofs[d], 1);
        w32[pos] = w;
        psrc[pos] = src16[i];
    }
}

// ---------- K6: CSR gather, wave per dst node, 8 edges in flight; fused ELU ----------
__global__ __launch_bounds__(256) void k_gather(const int* __restrict__ rowptr,
                                                const int* __restrict__ wofs,
                                                const float* __restrict__ w32,
                                                const unsigned short* __restrict__ psrc,
                                                const __bf16* __restrict__ whb,
                                                const float* __restrict__ Zp,
                                                float* __restrict__ out) {
    int gw = (blockIdx.x * 256 + (int)threadIdx.x) >> 6;   // dst node
    int lane = threadIdx.x & 63;
    int sub = lane >> 3;          // edge slot
    int cg  = lane & 7;           // channel group
    int beg = rowptr[gw];
    int end = wofs[gw];
    float Z = *Zp;
    float invZ = (Z > 0.0f) ? 1.0f / Z : 0.0f;

    float acc[8];
#pragma unroll
    for (int k = 0; k < 8; ++k) acc[k] = 0.0f;

    for (int j0 = beg; j0 < end; j0 += 8) {
        int j = j0 + sub;
        bool valid = j < end;
        int jj = valid ? j : beg;
        float t = valid ? w32[jj] : 0.0f;
        int s = psrc[jj];
        bfvec8 v = *(const bfvec8*)(whb + (size_t)s * OUT_CH + cg * 8);
#pragma unroll
        for (int k = 0; k < 8; ++k) acc[k] += t * (float)v[k];
    }

#pragma unroll
    for (int mask = 8; mask <= 32; mask <<= 1) {
#pragma unroll
        for (int k = 0; k < 8; ++k) acc[k] += __shfl_xor(acc[k], mask);
    }

    if (sub == 0) {
        floatx4 o0, o1;
#pragma unroll
        for (int k = 0; k < 4; ++k) {
            float h = acc[k] * invZ;
            o0[k] = h > 0.0f ? h : expf(h) - 1.0f;
        }
#pragma unroll
        for (int k = 0; k < 4; ++k) {
            float h = acc[4 + k] * invZ;
            o1[k] = h > 0.0f ? h : expf(h) - 1.0f;
        }
        float* dst = out + (size_t)gw * OUT_CH + cg * 8;
        *(floatx4*)(dst)     = o0;
        *(floatx4*)(dst + 4) = o1;
    }
}

extern "C" void kernel_launch(void* const* d_in, const int* in_sizes, int n_in,
                              void* d_out, int out_size, void* d_ws, size_t ws_size,
                              hipStream_t stream) {
    const void* x  = d_in[0];
    const int* ei  = (const int*)d_in[1];
    const void* W  = d_in[2];
    const void* a  = d_in[3];
    float* out     = (float*)d_out;

    char* ws = (char*)d_ws;
    __bf16* whb  = (__bf16*)(ws + WS_WHB);
    float* w32   = (float*)(ws + WS_W32);
    unsigned short* psrc  = (unsigned short*)(ws + WS_PSRC);
    unsigned short* src16 = (unsigned short*)(ws + WS_SRC16);
    unsigned short* dst16 = (unsigned short*)(ws + WS_DST16);
    float* we    = (float*)(ws + WS_WE);
    int* cnt     = (int*)(ws + WS_CNT);
    unsigned* keys = (unsigned*)(ws + WS_KEYS);
    int* rowptr  = (int*)(ws + WS_ROWP);
    int* wofs    = (int*)(ws + WS_WOFS);
    __bf16* Wth  = (__bf16*)(ws + WS_WTH);
    __bf16* Wtl  = (__bf16*)(ws + WS_WTL);
    float* esrc  = (float*)(ws + WS_ESRC);
    float* edst  = (float*)(ws + WS_EDST);
    float* bsum  = (float*)(ws + WS_BSUM);
    int*   btot  = (int*)(ws + WS_BTOT);
    int*   bbase = (int*)(ws + WS_BBASE);
    float* Z     = (float*)(ws + WS_Z);
    int*   flags = (int*)(ws + WS_FLAGS);

    // zero cnt + keys in one memset (keys: 0 == encode(-NaN), identity for max)
    hipMemsetAsync(cnt, 0, N_NODES * sizeof(int) + 8, stream);

    k_prep  <<<64,     256, 0, stream>>>(W, ei, (const unsigned*)x, flags, Wth, Wtl);
    k_mm    <<<782,    256, 0, stream>>>(x, Wth, Wtl, a, flags, whb, esrc, edst, keys);
    k_edge  <<<NBLK_E, 256, 0, stream>>>(ei, flags, keys, esrc, edst, src16, dst16, we, cnt, bsum);
    k_scanA <<<NBLK_N, 256, 0, stream>>>(cnt, rowptr, btot);
    k_scanB <<<1,      256, 0, stream>>>(btot, bbase, bsum, Z);
    k_scanC <<<NBLK_N, 256, 0, stream>>>(rowptr, wofs, bbase);
    k_place <<<NBLK_E, 256, 0, stream>>>(we, src16, dst16, wofs, w32, psrc);
    k_gather<<<N_NODES / 4, 256, 0, stream>>>(rowptr, wofs, w32, psrc, whb, Z, out);
}

// Round 12
// 197.209 us; speedup vs baseline: 1.2654x; 1.2654x over previous
//
#include <hip/hip_runtime.h>
#include <hip/hip_bf16.h>

#define N_NODES 50000
#define N_EDGES 800000
#define IN_CH 256
#define OUT_CH 64
#define NBLK_E 3125   // N_EDGES / 256
#define NBLK_N 196    // ceil(50000/256)

typedef __bf16 bfvec8 __attribute__((ext_vector_type(8)));
typedef float floatx4 __attribute__((ext_vector_type(4)));

// ---- ws layout (bytes), total ~18.7 MB ----
#define WS_WHB   0          // bf16 [50000][64]   6,400,000
#define WS_W32   6400000    // fp32 [800000]      3,200,000  CSR-placed weights
#define WS_PSRC  9600000    // u16  [800000]      1,600,000  CSR-placed src
#define WS_SRC16 11200000   // u16  [800000]      1,600,000
#define WS_DST16 12800000   // u16  [800000]      1,600,000
#define WS_WE    14400000   // fp32 [800000]      3,200,000  edge w (-1 = masked)
#define WS_CNT   17600000   // int  [50000]         200,000
#define WS_KEYS  17800000   // uint[2] {keyS,keyD}  (memset with CNT: 200,008 B)
#define WS_ROWP  17800016   // int  [50000]
#define WS_WOFS  18000016   // int  [50000]
#define WS_WTH   18200016   // bf16 [64][256]        32,768  (16B aligned)
#define WS_WTL   18232784   // bf16 [64][256]        32,768
#define WS_ESRC  18265552   // fp32 [50000]
#define WS_EDST  18465552   // fp32 [50000]
#define WS_BSUM  18665552   // fp32 [3125]
#define WS_BTOT  18678064   // int  [196]
#define WS_BBASE 18678848   // int  [196]
#define WS_Z     18679632
#define WS_FLAGS 18679636   // int[2]: {edge_is_i64, float_is_f32}

// ---------- helpers ----------
__device__ __forceinline__ unsigned encode_f(float f) {
    unsigned u = __float_as_uint(f);
    return (u & 0x80000000u) ? ~u : (u | 0x80000000u);
}
__device__ __forceinline__ float decode_f(unsigned u) {
    unsigned b = (u & 0x80000000u) ? (u & 0x7fffffffu) : ~u;
    return __uint_as_float(b);
}
__device__ __forceinline__ float loadf(const void* p, size_t i, int isf32) {
    return isf32 ? ((const float*)p)[i]
                 : __bfloat162float(((const __hip_bfloat16*)p)[i]);
}
__device__ __forceinline__ void load_edge(const int* __restrict__ ei, int i, int f64,
                                          int& s, int& d) {
    if (f64) {
        int2 ps = ((const int2*)ei)[i];
        int2 pd = ((const int2*)ei)[N_EDGES + i];
        s = ps.x; d = pd.x;
    } else {
        s = ei[i]; d = ei[N_EDGES + i];
    }
    s = min(max(s, 0), N_NODES - 1);
    d = min(max(d, 0), N_NODES - 1);
}

// ---------- K1: Wt hi/lo split-transpose; also computes dtype flags locally ----------
__global__ __launch_bounds__(256) void k_prep(const void* __restrict__ Wv,
                                              const int* __restrict__ ei,
                                              const unsigned* __restrict__ xw,
                                              int* __restrict__ flags,
                                              __bf16* __restrict__ Wth,
                                              __bf16* __restrict__ Wtl) {
    int t = threadIdx.x;
    int v = 0;
    for (int i = t; i < 2048; i += 256) v |= ei[2 * i + 1];   // i64 high words == 0
    unsigned lo = xw[t] & 0xFFFFu;
    unsigned e8 = (lo >> 7) & 0xFFu;
    int hit = (e8 >= 96u && e8 <= 144u) ? 1 : 0;              // bf16-packed: ~all hit
#pragma unroll
    for (int off = 32; off > 0; off >>= 1) {
        v |= __shfl_down(v, off);
        hit += __shfl_down(hit, off);
    }
    __shared__ int sv[4], sh[4];
    if ((t & 63) == 0) { sv[t >> 6] = v; sh[t >> 6] = hit; }
    __syncthreads();
    __shared__ int s_isf;
    if (t == 0) {
        int f64 = ((sv[0] | sv[1] | sv[2] | sv[3]) == 0) ? 1 : 0;
        int isf = ((sh[0] + sh[1] + sh[2] + sh[3]) < 192) ? 1 : 0;
        flags[0] = f64;
        flags[1] = isf;
        s_isf = isf;
    }
    __syncthreads();
    int isf = s_isf;

    int g = blockIdx.x * 256 + t;   // 0..16383
    int c = g >> 8, k = g & 255;
    float w = loadf(Wv, (size_t)k * OUT_CH + c, isf);
    __bf16 h = (__bf16)w;
    Wth[g] = h;
    Wtl[g] = (__bf16)(w - (float)h);
}

// ---------- K2: wh = x @ W via split-bf16 MFMA; Wt in LDS; fused logits + node max ----------
// node-max: per-block LDS reduce -> ONE atomicMax pair per block (was per-wave:
// 25K same-line atomics serialized at ~2.5ns each = +63us in round 11).
__global__ __launch_bounds__(256, 2) void k_mm(const void* __restrict__ xv,
                                               const __bf16* __restrict__ Wth,
                                               const __bf16* __restrict__ Wtl,
                                               const void* __restrict__ av,
                                               const int* __restrict__ flags,
                                               __bf16* __restrict__ whb,
                                               float* __restrict__ esrc,
                                               float* __restrict__ edst,
                                               unsigned* __restrict__ keys) {
    __shared__ __bf16 lW[2][64 * 256];        // 64 KB
    __shared__ float smS[4], smD[4];
    int tid = threadIdx.x;
    int isf = flags[1];
    int gw = (blockIdx.x * 256 + tid) >> 6;
    int lane = tid & 63;
    int wid = tid >> 6;
    int m = lane & 15, quad = lane >> 4;
    int nb = gw * 16;
    bool active = gw < N_NODES / 16;          // wave-uniform

    // hoisted x loads
    floatx4 x0[8], x1[8];
    bfvec8 xa[8];
    if (active) {
        if (isf) {
            const float* xr = (const float*)xv + (size_t)(nb + m) * IN_CH + quad * 8;
#pragma unroll
            for (int s = 0; s < 8; ++s) {
                x0[s] = *(const floatx4*)(xr + s * 32);
                x1[s] = *(const floatx4*)(xr + s * 32 + 4);
            }
        } else {
            const __bf16* xr = (const __bf16*)xv + (size_t)(nb + m) * IN_CH + quad * 8;
#pragma unroll
            for (int s = 0; s < 8; ++s) xa[s] = *(const bfvec8*)(xr + s * 32);
        }
    }

    // stage Wth/Wtl -> LDS, 16B chunks xor-swizzled (conflict-free ds_read_b128)
#pragma unroll
    for (int i = 0; i < 8; ++i) {
        int f = i * 256 + tid;
        int r = f >> 5, c = f & 31;
        int cs = c ^ (r & 31);
        *(bfvec8*)(&lW[0][r * 256 + cs * 8]) = *(const bfvec8*)(Wth + r * 256 + c * 8);
        *(bfvec8*)(&lW[1][r * 256 + cs * 8]) = *(const bfvec8*)(Wtl + r * 256 + c * 8);
    }
    __syncthreads();

    float mS = -3.0e38f, mD = -3.0e38f;
    if (active) {
        floatx4 acc[4];
#pragma unroll
        for (int ct = 0; ct < 4; ++ct) acc[ct] = (floatx4){0.f, 0.f, 0.f, 0.f};

        if (isf) {
#pragma unroll
            for (int s = 0; s < 8; ++s) {
                float v[8];
                *(floatx4*)(v)     = x0[s];
                *(floatx4*)(v + 4) = x1[s];
                bfvec8 ahi, alo;
#pragma unroll
                for (int j = 0; j < 8; ++j) {
                    __bf16 h = (__bf16)v[j];
                    ahi[j] = h;
                    alo[j] = (__bf16)(v[j] - (float)h);
                }
#pragma unroll
                for (int ct = 0; ct < 4; ++ct) {
                    int row = ct * 16 + m;
                    int cs = ((s * 4 + quad) ^ (row & 31)) * 8;
                    bfvec8 bhi = *(const bfvec8*)(&lW[0][row * 256 + cs]);
                    bfvec8 blo = *(const bfvec8*)(&lW[1][row * 256 + cs]);
                    acc[ct] = __builtin_amdgcn_mfma_f32_16x16x32_bf16(ahi, blo, acc[ct], 0, 0, 0);
                    acc[ct] = __builtin_amdgcn_mfma_f32_16x16x32_bf16(alo, bhi, acc[ct], 0, 0, 0);
                    acc[ct] = __builtin_amdgcn_mfma_f32_16x16x32_bf16(ahi, bhi, acc[ct], 0, 0, 0);
                }
            }
        } else {
#pragma unroll
            for (int s = 0; s < 8; ++s) {
#pragma unroll
                for (int ct = 0; ct < 4; ++ct) {
                    int row = ct * 16 + m;
                    int cs = ((s * 4 + quad) ^ (row & 31)) * 8;
                    bfvec8 bhi = *(const bfvec8*)(&lW[0][row * 256 + cs]);
                    bfvec8 blo = *(const bfvec8*)(&lW[1][row * 256 + cs]);
                    acc[ct] = __builtin_amdgcn_mfma_f32_16x16x32_bf16(xa[s], blo, acc[ct], 0, 0, 0);
                    acc[ct] = __builtin_amdgcn_mfma_f32_16x16x32_bf16(xa[s], bhi, acc[ct], 0, 0, 0);
                }
            }
        }

        float a1[4], a2[4];
#pragma unroll
        for (int ct = 0; ct < 4; ++ct) {
            a1[ct] = loadf(av, ct * 16 + m, isf);
            a2[ct] = loadf(av, OUT_CH + ct * 16 + m, isf);
        }
#pragma unroll
        for (int r = 0; r < 4; ++r) {
            int node = nb + quad * 4 + r;
            float s1 = 0.f, s2 = 0.f;
#pragma unroll
            for (int ct = 0; ct < 4; ++ct) {
                float vv = acc[ct][r];
                whb[(size_t)node * OUT_CH + ct * 16 + m] = (__bf16)vv;
                s1 += vv * a1[ct];
                s2 += vv * a2[ct];
            }
#pragma unroll
            for (int off = 1; off < 16; off <<= 1) {
                s1 += __shfl_xor(s1, off);
                s2 += __shfl_xor(s2, off);
            }
            if (m == 0) { esrc[node] = s1; edst[node] = s2; }
            mS = fmaxf(mS, s1);
            mD = fmaxf(mD, s2);
        }
#pragma unroll
        for (int mask = 16; mask <= 32; mask <<= 1) {
            mS = fmaxf(mS, __shfl_xor(mS, mask));
            mD = fmaxf(mD, __shfl_xor(mD, mask));
        }
    }
    if (lane == 0) { smS[wid] = mS; smD[wid] = mD; }
    __syncthreads();
    if (tid == 0) {
        float aS = fmaxf(fmaxf(smS[0], smS[1]), fmaxf(smS[2], smS[3]));
        float aD = fmaxf(fmaxf(smD[0], smD[1]), fmaxf(smD[2], smD[3]));
        atomicMax(&keys[0], encode_f(aS));   // keys memset to 0 == identity for max
        atomicMax(&keys[1], encode_f(aD));
    }
}

// ---------- K3: fused edge pass: score, exp(v-M'), histogram, block-sum, we[] ----------
__global__ __launch_bounds__(256) void k_edge(const int* __restrict__ ei,
                                              const int* __restrict__ flags,
                                              const unsigned* __restrict__ keys,
                                              const float* __restrict__ esrc,
                                              const float* __restrict__ edst,
                                              unsigned short* __restrict__ src16,
                                              unsigned short* __restrict__ dst16,
                                              float* __restrict__ we,
                                              int* __restrict__ cnt,
                                              float* __restrict__ bsum) {
    int f64 = flags[0];
    float Mp = decode_f(keys[0]) + decode_f(keys[1]);   // shift bound >= true max
    int i = blockIdx.x * 256 + threadIdx.x;
    int s, d;
    load_edge(ei, i, f64, s, d);
    src16[i] = (unsigned short)s;
    dst16[i] = (unsigned short)d;
    float v = esrc[s] + edst[d];
    float w, t;
    if (v > 0.0f) {
        w = expf(v - Mp);            // <= 1, no overflow; underflow -> 0 (placed, harmless)
        t = w;
        atomicAdd(&cnt[d], 1);
    } else {
        w = -1.0f;                   // sentinel: masked edge (true weight exactly 0)
        t = 0.0f;
    }
    we[i] = w;
#pragma unroll
    for (int off = 32; off > 0; off >>= 1) t += __shfl_down(t, off);
    __shared__ float sm[4];
    if ((threadIdx.x & 63) == 0) sm[threadIdx.x >> 6] = t;
    __syncthreads();
    if (threadIdx.x == 0) bsum[blockIdx.x] = sm[0] + sm[1] + sm[2] + sm[3];
}

// ---------- K4a: per-block scan of cnt ----------
__global__ __launch_bounds__(256) void k_scanA(const int* __restrict__ cnt,
                                               int* __restrict__ rowptr,
                                               int* __restrict__ btot) {
    int t = threadIdx.x, lane = t & 63, wid = t >> 6;
    int idx = blockIdx.x * 256 + t;
    int v = (idx < N_NODES) ? cnt[idx] : 0;
    int incl = v;
#pragma unroll
    for (int off = 1; off < 64; off <<= 1) {
        int u = __shfl_up(incl, off);
        if (lane >= off) incl += u;
    }
    __shared__ int wsum[4];
    if (lane == 63) wsum[wid] = incl;
    __syncthreads();
    int wbase = 0;
#pragma unroll
    for (int w = 0; w < 4; ++w) if (w < wid) wbase += wsum[w];
    if (idx < N_NODES) rowptr[idx] = wbase + incl - v;
    if (t == 255) btot[blockIdx.x] = wbase + incl;
}

// ---------- K4b: scan block totals + reduce bsum -> Z ----------
__global__ __launch_bounds__(256) void k_scanB(const int* __restrict__ btot,
                                               int* __restrict__ bbase,
                                               const float* __restrict__ bsum,
                                               float* __restrict__ Z) {
    int t = threadIdx.x, lane = t & 63, wid = t >> 6;
    float zs = 0.0f;
    for (int i = t; i < NBLK_E; i += 256) zs += bsum[i];
#pragma unroll
    for (int off = 32; off > 0; off >>= 1) zs += __shfl_down(zs, off);
    __shared__ float sz[4];
    if (lane == 0) sz[wid] = zs;

    int v = (t < NBLK_N) ? btot[t] : 0;
    int incl = v;
#pragma unroll
    for (int off = 1; off < 64; off <<= 1) {
        int u = __shfl_up(incl, off);
        if (lane >= off) incl += u;
    }
    __shared__ int wsum[4];
    if (lane == 63) wsum[wid] = incl;
    __syncthreads();
    int wbase = 0;
#pragma unroll
    for (int w = 0; w < 4; ++w) if (w < wid) wbase += wsum[w];
    if (t < NBLK_N) bbase[t] = wbase + incl - v;
    if (t == 0) *Z = sz[0] + sz[1] + sz[2] + sz[3];
}

// ---------- K4c: add block bases ----------
__global__ __launch_bounds__(256) void k_scanC(int* __restrict__ rowptr,
                                               int* __restrict__ wofs,
                                               const int* __restrict__ bbase) {
    int idx = blockIdx.x * 256 + threadIdx.x;
    if (idx < N_NODES) {
        int r = rowptr[idx] + bbase[blockIdx.x];
        rowptr[idx] = r;
        wofs[idx] = r;
    }
}

// ---------- K5: CSR placement ----------
__global__ __launch_bounds__(256) void k_place(const float* __restrict__ we,
                                               const unsigned short* __restrict__ src16,
                                               const unsigned short* __restrict__ dst16,
                                               int* __restrict__ wofs,
                                               float* __restrict__ w32,
                                               unsigned short* __restrict__ psrc) {
    int i = blockIdx.x * 256 + threadIdx.x;
    float w = we[i];
    if (w >= 0.0f) {
        int d = dst16[i];
        int pos = atomicAdd(&wofs[d], 1);
        w32[pos] = w;
        psrc[pos] = src16[i];
    }
}

// ---------- K6: CSR gather, wave per dst node, 8 edges in flight; fused ELU ----------
__global__ __launch_bounds__(256) void k_gather(const int* __restrict__ rowptr,
                                                const int* __restrict__ wofs,
                                                const float* __restrict__ w32,
                                                const unsigned short* __restrict__ psrc,
                                                const __bf16* __restrict__ whb,
                                                const float* __restrict__ Zp,
                                                float* __restrict__ out) {
    int gw = (blockIdx.x * 256 + (int)threadIdx.x) >> 6;   // dst node
    int lane = threadIdx.x & 63;
    int sub = lane >> 3;          // edge slot
    int cg  = lane & 7;           // channel group
    int beg = rowptr[gw];
    int end = wofs[gw];
    float Z = *Zp;
    float invZ = (Z > 0.0f) ? 1.0f / Z : 0.0f;

    float acc[8];
#pragma unroll
    for (int k = 0; k < 8; ++k) acc[k] = 0.0f;

    for (int j0 = beg; j0 < end; j0 += 8) {
        int j = j0 + sub;
        bool valid = j < end;
        int jj = valid ? j : beg;
        float t = valid ? w32[jj] : 0.0f;
        int s = psrc[jj];
        bfvec8 v = *(const bfvec8*)(whb + (size_t)s * OUT_CH + cg * 8);
#pragma unroll
        for (int k = 0; k < 8; ++k) acc[k] += t * (float)v[k];
    }

#pragma unroll
    for (int mask = 8; mask <= 32; mask <<= 1) {
#pragma unroll
        for (int k = 0; k < 8; ++k) acc[k] += __shfl_xor(acc[k], mask);
    }

    if (sub == 0) {
        floatx4 o0, o1;
#pragma unroll
        for (int k = 0; k < 4; ++k) {
            float h = acc[k] * invZ;
            o0[k] = h > 0.0f ? h : expf(h) - 1.0f;
        }
#pragma unroll
        for (int k = 0; k < 4; ++k) {
            float h = acc[4 + k] * invZ;
            o1[k] = h > 0.0f ? h : expf(h) - 1.0f;
        }
        float* dst = out + (size_t)gw * OUT_CH + cg * 8;
        *(floatx4*)(dst)     = o0;
        *(floatx4*)(dst + 4) = o1;
    }
}

extern "C" void kernel_launch(void* const* d_in, const int* in_sizes, int n_in,
                              void* d_out, int out_size, void* d_ws, size_t ws_size,
                              hipStream_t stream) {
    const void* x  = d_in[0];
    const int* ei  = (const int*)d_in[1];
    const void* W  = d_in[2];
    const void* a  = d_in[3];
    float* out     = (float*)d_out;

    char* ws = (char*)d_ws;
    __bf16* whb  = (__bf16*)(ws + WS_WHB);
    float* w32   = (float*)(ws + WS_W32);
    unsigned short* psrc  = (unsigned short*)(ws + WS_PSRC);
    unsigned short* src16 = (unsigned short*)(ws + WS_SRC16);
    unsigned short* dst16 = (unsigned short*)(ws + WS_DST16);
    float* we    = (float*)(ws + WS_WE);
    int* cnt     = (int*)(ws + WS_CNT);
    unsigned* keys = (unsigned*)(ws + WS_KEYS);
    int* rowptr  = (int*)(ws + WS_ROWP);
    int* wofs    = (int*)(ws + WS_WOFS);
    __bf16* Wth  = (__bf16*)(ws + WS_WTH);
    __bf16* Wtl  = (__bf16*)(ws + WS_WTL);
    float* esrc  = (float*)(ws + WS_ESRC);
    float* edst  = (float*)(ws + WS_EDST);
    float* bsum  = (float*)(ws + WS_BSUM);
    int*   btot  = (int*)(ws + WS_BTOT);
    int*   bbase = (int*)(ws + WS_BBASE);
    float* Z     = (float*)(ws + WS_Z);
    int*   flags = (int*)(ws + WS_FLAGS);

    // zero cnt + keys in one memset (keys: 0 == identity for encoded max)
    hipMemsetAsync(cnt, 0, N_NODES * sizeof(int) + 8, stream);

    k_prep  <<<64,     256, 0, stream>>>(W, ei, (const unsigned*)x, flags, Wth, Wtl);
    k_mm    <<<782,    256, 0, stream>>>(x, Wth, Wtl, a, flags, whb, esrc, edst, keys);
    k_edge  <<<NBLK_E, 256, 0, stream>>>(ei, flags, keys, esrc, edst, src16, dst16, we, cnt, bsum);
    k_scanA <<<NBLK_N, 256, 0, stream>>>(cnt, rowptr, btot);
    k_scanB <<<1,      256, 0, stream>>>(btot, bbase, bsum, Z);
    k_scanC <<<NBLK_N, 256, 0, stream>>>(rowptr, wofs, bbase);
    k_place <<<NBLK_E, 256, 0, stream>>>(we, src16, dst16, wofs, w32, psrc);
    k_gather<<<N_NODES / 4, 256, 0, stream>>>(rowptr, wofs, w32, psrc, whb, Z, out);
}